// Round 9
// baseline (118.077 us; speedup 1.0000x reference)
//
#include <hip/hip_runtime.h>
#include <hip/hip_bf16.h>

typedef __bf16 bf16x8 __attribute__((ext_vector_type(8)));
typedef float  f32x4  __attribute__((ext_vector_type(4)));

#define VOCAB 24
#define EDIM  16
#define HDIM  32
#define TLEN  128

union A2U { int4 w; bf16x8 v; };

__device__ __forceinline__ float xor8f(float v) {
    // lane <- lane^8 within each 16-lane row (row_ror:8; VALU DPP, no LDS)
    int r = __builtin_amdgcn_update_dpp(0, __float_as_int(v), 0x128, 0xF, 0xF, true);
    return __int_as_float(r);
}
// B-matrices pre-scaled by -log2(e) (sigmoid cols) / -2*log2(e) (tanh cols):
__device__ __forceinline__ float rsig(float a) {   // sigmoid from scaled acc
    return __builtin_amdgcn_rcpf(1.0f + __builtin_amdgcn_exp2f(a));
}
__device__ __forceinline__ float fast_tanh(float x) {
    float t = __builtin_amdgcn_exp2f(x * -2.88539008f);
    return fmaf(2.0f, __builtin_amdgcn_rcpf(1.0f + t), -1.0f);
}

// LDS-only sync: waits this wave's ds ops, then barrier. Does NOT drain
// vmcnt -> global token prefetches stay in flight across steps.
__device__ __forceinline__ void block_sync_lds() {
    asm volatile("s_waitcnt lgkmcnt(0)" ::: "memory");
    __builtin_amdgcn_s_barrier();
    asm volatile("" ::: "memory");
}

// Block = 4 waves, ONE 16-row batch group (1024 blocks -> 4 blocks/CU ->
// 4 waves/SIMD; this round isolates occupancy with the slim body).
// Wave w owns hidden j in [8w,8w+8). Permuted-column tiles: tile p, col n ->
// gate q = 2p+(n>>3), hidden j = 8w+(n&7); tile0={i|f}, tile1={g|o}.
// Gate sharing lane<->lane^8 via DPP row_ror:8. Low lanes update rows
// 4hi+{0,1}, high lanes 4hi+{2,3}. Slot order: barrier -> h ds_reads ->
// one-hot + gates_x MFMAs (latency filler) -> h-MFMAs -> update -> writes.
__global__ __launch_bounds__(256, 4) void lstm_fused(
    const int*   __restrict__ x,     // [B][128]
    const float* __restrict__ emb,   // [24][16]
    const float* __restrict__ W_ih,  // [128][16]
    const float* __restrict__ W_hh,  // [128][32]
    const float* __restrict__ b_ih,  // [128]
    const float* __restrict__ b_hh,  // [128]
    const float* __restrict__ fc_w,  // [2][32]
    const float* __restrict__ fc_b,  // [2]
    float*       __restrict__ out)   // [B][2]
{
    __shared__ __align__(16) __bf16 hbuf[2][16][40];  // h dbuf, 80B rows
    __shared__ __align__(16) float  fbuf[16][33];     // final h (f32) for FC

    const int tid   = threadIdx.x;
    const int wid   = tid >> 6;
    const int lane  = tid & 63;
    const int l15   = lane & 15;
    const int hi    = lane >> 4;
    const int kbase = hi * 8;
    const int kh    = hi * 4;            // packed-word index base
    const int row0  = blockIdx.x * 16;
    const bool lowj = (l15 < 8);
    const int  j    = wid * 8 + (l15 & 7);

    // ---- B-fragments (permuted gate columns), pre-scaled, registers ----
    bf16x8 b1f[2];  // scale * W_hh^T
    bf16x8 b2f[2];  // scale * (emb[v].W_ih[gcol] + b_ih+b_hh)
    #pragma unroll
    for (int p = 0; p < 2; ++p) {
        const int q    = 2 * p + (l15 >> 3);
        const int gcol = q * 32 + j;
        const float scale = (q == 2) ? -2.88539008f : -1.44269504f;
        const float* wrow = W_hh + gcol * HDIM;
        #pragma unroll
        for (int i = 0; i < 8; ++i)
            b1f[p][i] = (__bf16)(scale * wrow[kbase + i]);
        const float bias = b_ih[gcol] + b_hh[gcol];
        const float* wi = W_ih + gcol * EDIM;
        #pragma unroll
        for (int i = 0; i < 8; ++i) {
            const int v = kbase + i;
            float s = 0.0f;
            if (v < VOCAB) {
                s = bias;
                #pragma unroll
                for (int e = 0; e < EDIM; ++e)
                    s += emb[v * EDIM + e] * wi[e];
            }
            b2f[p][i] = (__bf16)(scale * s);
        }
    }

    const float a1c  = lowj ?  2.0f : 1.0f;   // tile1: g->tanh, o->sigmoid
    const float b1c  = lowj ? -1.0f : 0.0f;
    const int   urow = 4 * hi + (lowj ? 0 : 2);

    float c0 = 0.0f, c1 = 0.0f;
    const int* xrow = x + (row0 + l15) * TLEN;
    const f32x4 z = {0.f, 0.f, 0.f, 0.f};

#define ONEHOT(DST, XV) do {                                                   \
    const int xv_   = (XV);                                                    \
    const int hotw_ = 0x3F80 << ((xv_ & 1) << 4);                              \
    const int hoth_ = xv_ >> 1;                                                \
    DST.w.x = (hoth_ == kh + 0) ? hotw_ : 0;                                   \
    DST.w.y = (hoth_ == kh + 1) ? hotw_ : 0;                                   \
    DST.w.z = (hoth_ == kh + 2) ? hotw_ : 0;                                   \
    DST.w.w = (hoth_ == kh + 3) ? hotw_ : 0;                                   \
} while (0)

#define GUPD(A0, A1, C0, C1, HV0, HV1) do {                                    \
    const float s00_ = rsig(A0[0]), s01_ = rsig(A0[1]);                        \
    const float s02_ = rsig(A0[2]), s03_ = rsig(A0[3]);                        \
    const float s10_ = fmaf(a1c, rsig(A1[0]), b1c);                            \
    const float s11_ = fmaf(a1c, rsig(A1[1]), b1c);                            \
    const float s12_ = fmaf(a1c, rsig(A1[2]), b1c);                            \
    const float s13_ = fmaf(a1c, rsig(A1[3]), b1c);                            \
    const float x00_ = xor8f(s00_), x01_ = xor8f(s01_);                        \
    const float x02_ = xor8f(s02_), x03_ = xor8f(s03_);                        \
    const float x10_ = xor8f(s10_), x11_ = xor8f(s11_);                        \
    const float x12_ = xor8f(s12_), x13_ = xor8f(s13_);                        \
    const float iv0_ = lowj ? s00_ : x02_;                                     \
    const float fv0_ = lowj ? x00_ : s02_;                                     \
    const float gv0_ = lowj ? s10_ : x12_;                                     \
    const float ov0_ = lowj ? x10_ : s12_;                                     \
    C0 = fmaf(fv0_, C0, iv0_ * gv0_);                                          \
    HV0 = ov0_ * fast_tanh(C0);                                                \
    const float iv1_ = lowj ? s01_ : x03_;                                     \
    const float fv1_ = lowj ? x01_ : s03_;                                     \
    const float gv1_ = lowj ? s11_ : x13_;                                     \
    const float ov1_ = lowj ? x11_ : s13_;                                     \
    C1 = fmaf(fv1_, C1, iv1_ * gv1_);                                          \
    HV1 = ov1_ * fast_tanh(C1);                                                \
} while (0)

// One timestep. P = t&1 (compile-time). XV = THIS step's token.
#define SLOT(P, FIRST, LAST, XV) do {                                          \
    bf16x8 a1_;                                                                \
    if (!(FIRST)) {                                                            \
        block_sync_lds();                                                      \
        a1_ = *(const bf16x8*)&hbuf[(P) ^ 1][l15][kbase];                      \
    }                                                                          \
    A2U a2_;                                                                   \
    ONEHOT(a2_, XV);                                                           \
    f32x4 a0_ = __builtin_amdgcn_mfma_f32_16x16x32_bf16(a2_.v, b2f[0], z, 0, 0, 0); \
    f32x4 a1t_ = __builtin_amdgcn_mfma_f32_16x16x32_bf16(a2_.v, b2f[1], z, 0, 0, 0); \
    if (!(FIRST)) {                                                            \
        a0_  = __builtin_amdgcn_mfma_f32_16x16x32_bf16(a1_, b1f[0], a0_,  0, 0, 0); \
        a1t_ = __builtin_amdgcn_mfma_f32_16x16x32_bf16(a1_, b1f[1], a1t_, 0, 0, 0); \
    }                                                                          \
    float hv0_, hv1_;                                                          \
    GUPD(a0_, a1t_, c0, c1, hv0_, hv1_);                                       \
    if (!(LAST)) {                                                             \
        hbuf[P][urow    ][j] = (__bf16)hv0_;                                   \
        hbuf[P][urow + 1][j] = (__bf16)hv1_;                                   \
    } else {                                                                   \
        fbuf[urow    ][j] = hv0_;                                              \
        fbuf[urow + 1][j] = hv1_;                                              \
    }                                                                          \
} while (0)

    // ---- prologue: tokens 0-3 and 4-7 ----
    int4 q0 = *(const int4*)xrow;
    int4 xq = *(const int4*)(xrow + 4);

    // t = 0..3
    SLOT(0, true,  false, q0.x);
    SLOT(1, false, false, q0.y);
    SLOT(0, false, false, q0.z);
    SLOT(1, false, false, q0.w);

    // main: t = 4 .. 123. Entering with xq = tokens[t..t+3];
    // prefetch tokens[t+4..t+7] (stays in flight across lgkm-only barriers).
    #pragma unroll 1
    for (int t = 4; t < 124; t += 4) {
        const int4 n = *(const int4*)(xrow + t + 4);
        SLOT(0, false, false, xq.x);   // t
        SLOT(1, false, false, xq.y);   // t+1
        SLOT(0, false, false, xq.z);   // t+2
        SLOT(1, false, false, xq.w);   // t+3
        xq = n;
    }

    // tail: t = 124..127
    SLOT(0, false, false, xq.x);       // 124
    SLOT(1, false, false, xq.y);       // 125
    SLOT(0, false, false, xq.z);       // 126
    SLOT(1, false, true,  xq.w);       // 127 -> fbuf

#undef SLOT
#undef GUPD
#undef ONEHOT

    __syncthreads();   // final: fbuf visible (full drain fine here, once)

    // ---- FC epilogue: out[b] = h_last[b] @ fc_w^T + fc_b ----
    if (tid < 16) {
        float o0 = fc_b[0], o1 = fc_b[1];
        #pragma unroll
        for (int jj = 0; jj < HDIM; ++jj) {
            const float h = fbuf[tid][jj];
            o0 += fc_w[jj]        * h;
            o1 += fc_w[HDIM + jj] * h;
        }
        float2 res;
        res.x = o0; res.y = o1;
        *(float2*)&out[(row0 + tid) * 2] = res;
    }
}

extern "C" void kernel_launch(void* const* d_in, const int* in_sizes, int n_in,
                              void* d_out, int out_size, void* d_ws, size_t ws_size,
                              hipStream_t stream) {
    const int*   x    = (const int*)  d_in[0];
    const float* emb  = (const float*)d_in[1];
    const float* W_ih = (const float*)d_in[2];
    const float* W_hh = (const float*)d_in[3];
    const float* b_ih = (const float*)d_in[4];
    const float* b_hh = (const float*)d_in[5];
    const float* fc_w = (const float*)d_in[6];
    const float* fc_b = (const float*)d_in[7];
    float* out = (float*)d_out;

    const int B    = in_sizes[0] / TLEN;   // 16384
    const int nblk = B / 16;               // 1024 blocks x 4 waves, 4 blocks/CU

    lstm_fused<<<nblk, 256, 0, stream>>>(x, emb, W_ih, W_hh, b_ih, b_hh, fc_w, fc_b, out);
}

// Round 10
// 110.059 us; speedup vs baseline: 1.0728x; 1.0728x over previous
//
#include <hip/hip_runtime.h>
#include <hip/hip_bf16.h>

typedef __bf16 bf16x8 __attribute__((ext_vector_type(8)));
typedef float  f32x4  __attribute__((ext_vector_type(4)));

#define VOCAB 24
#define EDIM  16
#define HDIM  32
#define TLEN  128

union A2U { int4 w; bf16x8 v; };

// B-matrices pre-scaled by -log2(e) (sigmoid cols i,f,o) / -2*log2(e) (tanh
// col g), so gate activations are multiply-free:
__device__ __forceinline__ float rsig(float a) {   // sigmoid from scaled acc
    return __builtin_amdgcn_rcpf(1.0f + __builtin_amdgcn_exp2f(a));
}
__device__ __forceinline__ float fast_tanh(float x) {
    float t = __builtin_amdgcn_exp2f(x * -2.88539008f);
    return fmaf(2.0f, __builtin_amdgcn_rcpf(1.0f + t), -1.0f);
}

// WAVE-PRIVATE design: block = 1 wave = 16 batch rows, ALL 128 gate columns.
// No inter-wave exchange -> NO barrier in the recurrence (R4-R8 showed the
// phase-locked block barrier is the invariant ~40us idle).
// Per step: 8 one-hot MFMAs (gates_x, pipelined one step ahead on the MFMA
// pipe) + 8 h-MFMAs; C-layout makes all 4 gates of element (row, j)
// lane-local: acc[2q+(j>>4)][reg] with col j&15=l15, row 4hi+reg.
// h crosses lanes through a wave-private LDS buffer; in-wave write->read
// ordering is enforced by compiler-inserted lgkmcnt (no s_barrier needed).
__global__ __launch_bounds__(64) void lstm_fused(
    const int*   __restrict__ x,     // [B][128]
    const float* __restrict__ emb,   // [24][16]
    const float* __restrict__ W_ih,  // [128][16]
    const float* __restrict__ W_hh,  // [128][32]
    const float* __restrict__ b_ih,  // [128]
    const float* __restrict__ b_hh,  // [128]
    const float* __restrict__ fc_w,  // [2][32]
    const float* __restrict__ fc_b,  // [2]
    float*       __restrict__ out)   // [B][2]
{
    __shared__ __align__(16) __bf16 hbuf[16][40];  // wave-private h, 80B rows
    __shared__ __align__(16) float  fbuf[16][33];  // final h (f32) for FC

    const int lane  = threadIdx.x;       // 0..63
    const int l15   = lane & 15;
    const int hi    = lane >> 4;         // 0..3
    const int kbase = hi * 8;
    const int kh    = hi * 4;            // packed-word index base
    const int row0  = blockIdx.x * 16;

    // ---- B-fragments for all 8 column tiles, pre-scaled, registers ----
    // tile nt covers gate cols 16nt..16nt+15; gate id q = nt>>1
    // (q: 0=i, 1=f, 2=g, 3=o). B-frag: n = l15, k = kbase + i.
    bf16x8 b1f[8];  // scale * W_hh^T
    bf16x8 b2f[8];  // scale * (emb[v].W_ih[gcol] + b_ih + b_hh)
    #pragma unroll
    for (int nt = 0; nt < 8; ++nt) {
        const int gcol = nt * 16 + l15;
        const float scale = ((nt >> 1) == 2) ? -2.88539008f : -1.44269504f;
        const float* wrow = W_hh + gcol * HDIM;
        #pragma unroll
        for (int i = 0; i < 8; ++i)
            b1f[nt][i] = (__bf16)(scale * wrow[kbase + i]);
        const float bias = b_ih[gcol] + b_hh[gcol];
        const float* wi = W_ih + gcol * EDIM;
        #pragma unroll
        for (int i = 0; i < 8; ++i) {
            const int v = kbase + i;
            float s = 0.0f;
            if (v < VOCAB) {
                s = bias;
                #pragma unroll
                for (int e = 0; e < EDIM; ++e)
                    s += emb[v * EDIM + e] * wi[e];
            }
            b2f[nt][i] = (__bf16)(scale * s);
        }
    }

    float c[8];
    #pragma unroll
    for (int q = 0; q < 8; ++q) c[q] = 0.0f;

    f32x4 p[8];     // pipelined gates_x accumulators (token of NEXT slot)
    f32x4 acc[8];
    const f32x4 z = {0.f, 0.f, 0.f, 0.f};
    const int* xrow = x + (row0 + l15) * TLEN;

// one-hot gates_x MFMAs for token XV -> p[]
#define PRECOMP(XV) do {                                                       \
    const int xv_   = (XV);                                                    \
    const int hotw_ = 0x3F80 << ((xv_ & 1) << 4);                              \
    const int hoth_ = xv_ >> 1;                                                \
    A2U a2_;                                                                   \
    a2_.w.x = (hoth_ == kh + 0) ? hotw_ : 0;                                   \
    a2_.w.y = (hoth_ == kh + 1) ? hotw_ : 0;                                   \
    a2_.w.z = (hoth_ == kh + 2) ? hotw_ : 0;                                   \
    a2_.w.w = (hoth_ == kh + 3) ? hotw_ : 0;                                   \
    _Pragma("unroll")                                                          \
    for (int nt = 0; nt < 8; ++nt)                                             \
        p[nt] = __builtin_amdgcn_mfma_f32_16x16x32_bf16(a2_.v, b2f[nt], z, 0, 0, 0); \
} while (0)

// One timestep. On entry p[] holds this step's gates_x. XVN = NEXT token.
// acc value (nt, r): gate col = 16nt + l15, row = 4hi + r. Element (row,
// j=qq*16+l15): i=acc[qq], f=acc[qq+2], g=acc[qq+4], o=acc[qq+6] - lane-local.
#define SLOT(FIRST, LAST, XVN) do {                                            \
    if (FIRST) {                                                               \
        _Pragma("unroll")                                                      \
        for (int nt = 0; nt < 8; ++nt) acc[nt] = p[nt];                        \
    } else {                                                                   \
        const bf16x8 a1_ = *(const bf16x8*)&hbuf[l15][kbase];                  \
        _Pragma("unroll")                                                      \
        for (int nt = 0; nt < 8; ++nt)                                         \
            acc[nt] = __builtin_amdgcn_mfma_f32_16x16x32_bf16(a1_, b1f[nt], p[nt], 0, 0, 0); \
    }                                                                          \
    if (!(LAST)) { PRECOMP(XVN); }   /* fills MFMA pipe under GUPD VALU */     \
    _Pragma("unroll")                                                          \
    for (int qq = 0; qq < 2; ++qq) {                                           \
        _Pragma("unroll")                                                      \
        for (int r = 0; r < 4; ++r) {                                          \
            const float iv = rsig(acc[qq    ][r]);                             \
            const float fv = rsig(acc[qq + 2][r]);                             \
            const float gv = fmaf(2.0f, rsig(acc[qq + 4][r]), -1.0f);          \
            const float ov = rsig(acc[qq + 6][r]);                             \
            c[qq * 4 + r] = fmaf(fv, c[qq * 4 + r], iv * gv);                  \
            const float hv = ov * fast_tanh(c[qq * 4 + r]);                    \
            if (!(LAST)) hbuf[4 * hi + r][qq * 16 + l15] = (__bf16)hv;         \
            else         fbuf[4 * hi + r][qq * 16 + l15] = hv;                 \
        }                                                                      \
    }                                                                          \
} while (0)

    // ---- prologue: tokens 0-3 and 4-7; gates_x for t=0 ----
    int4 q0 = *(const int4*)xrow;
    int4 xq = *(const int4*)(xrow + 4);
    PRECOMP(q0.x);

    // t = 0..3
    SLOT(true,  false, q0.y);
    SLOT(false, false, q0.z);
    SLOT(false, false, q0.w);
    SLOT(false, false, xq.x);

    // main: t = 4..123, 4 steps/iter. Entering with xq = tokens[t..t+3];
    // prefetch tokens[t+4..t+7] at top (no barriers -> stays in flight).
    #pragma unroll 1
    for (int t = 4; t < 124; t += 4) {
        const int4 n = *(const int4*)(xrow + t + 4);
        SLOT(false, false, xq.y);   // t
        SLOT(false, false, xq.z);   // t+1
        SLOT(false, false, xq.w);   // t+2
        SLOT(false, false, n.x);    // t+3
        xq = n;
    }

    // tail: t = 124..127 (xq = tokens 124..127)
    SLOT(false, false, xq.y);       // 124
    SLOT(false, false, xq.z);       // 125
    SLOT(false, false, xq.w);       // 126
    SLOT(false, true,  0);          // 127 -> fbuf (f32)

#undef SLOT
#undef PRECOMP

    __syncthreads();   // single wave: just guarantees lgkm drain before FC

    // ---- FC epilogue: out[b] = h_last[b] @ fc_w^T + fc_b ----
    if (lane < 16) {
        float o0 = fc_b[0], o1 = fc_b[1];
        #pragma unroll
        for (int jj = 0; jj < HDIM; ++jj) {
            const float h = fbuf[lane][jj];
            o0 += fc_w[jj]        * h;
            o1 += fc_w[HDIM + jj] * h;
        }
        float2 res;
        res.x = o0; res.y = o1;
        *(float2*)&out[(row0 + lane) * 2] = res;
    }
}

extern "C" void kernel_launch(void* const* d_in, const int* in_sizes, int n_in,
                              void* d_out, int out_size, void* d_ws, size_t ws_size,
                              hipStream_t stream) {
    const int*   x    = (const int*)  d_in[0];
    const float* emb  = (const float*)d_in[1];
    const float* W_ih = (const float*)d_in[2];
    const float* W_hh = (const float*)d_in[3];
    const float* b_ih = (const float*)d_in[4];
    const float* b_hh = (const float*)d_in[5];
    const float* fc_w = (const float*)d_in[6];
    const float* fc_b = (const float*)d_in[7];
    float* out = (float*)d_out;

    const int B    = in_sizes[0] / TLEN;   // 16384
    const int nblk = B / 16;               // 1024 waves, 1 per SIMD chip-wide

    lstm_fused<<<nblk, 64, 0, stream>>>(x, emb, W_ih, W_hh, b_ih, b_hh, fc_w, fc_b, out);
}